// Round 1
// baseline (192.807 us; speedup 1.0000x reference)
//
#include <hip/hip_runtime.h>
#include <math.h>

#define BM 64
#define BN 64
#define BK 16

// C = tanh(A@W + bias), A: MxK, W: KxN, C: MxN
__global__ __launch_bounds__(256) void k_gemm_tanh(
    const float* __restrict__ A, const float* __restrict__ W,
    const float* __restrict__ bias, float* __restrict__ C,
    int M, int N, int K)
{
  __shared__ float As[BK][BM + 4];
  __shared__ float Bs[BK][BN + 4];
  const int tid = threadIdx.x;
  const int n0 = blockIdx.x * BN;
  const int m0 = blockIdx.y * BM;
  const int tx = tid & 15;   // n sub-tile
  const int ty = tid >> 4;   // m sub-tile
  const int lk  = tid & 15;  // A-load: k
  const int lmb = tid >> 4;  // A-load: m base
  const int lnn = tid & 63;  // B-load: n
  const int lkb = tid >> 6;  // B-load: k base
  float acc[4][4] = {};
  for (int k0 = 0; k0 < K; k0 += BK) {
#pragma unroll
    for (int i = 0; i < 4; ++i) {
      const int m = lmb + 16 * i;
      As[lk][m] = A[(size_t)(m0 + m) * K + (k0 + lk)];
    }
#pragma unroll
    for (int i = 0; i < 4; ++i) {
      const int kk = lkb + 4 * i;
      Bs[kk][lnn] = W[(size_t)(k0 + kk) * N + (n0 + lnn)];
    }
    __syncthreads();
#pragma unroll
    for (int kk = 0; kk < BK; ++kk) {
      float a[4], b[4];
#pragma unroll
      for (int i = 0; i < 4; ++i) a[i] = As[kk][ty * 4 + i];
#pragma unroll
      for (int j = 0; j < 4; ++j) b[j] = Bs[kk][tx * 4 + j];
#pragma unroll
      for (int i = 0; i < 4; ++i)
#pragma unroll
        for (int j = 0; j < 4; ++j)
          acc[i][j] = fmaf(a[i], b[j], acc[i][j]);
    }
    __syncthreads();
  }
#pragma unroll
  for (int i = 0; i < 4; ++i) {
    const int m = m0 + ty * 4 + i;
#pragma unroll
    for (int j = 0; j < 4; ++j) {
      const int n = n0 + tx * 4 + j;
      C[(size_t)m * N + n] = tanhf(acc[i][j] + bias[n]);
    }
  }
}

// C = A@W + bias + X (residual), A: MxK, W: KxN, X,C: MxN
__global__ __launch_bounds__(256) void k_gemm_resid(
    const float* __restrict__ A, const float* __restrict__ W,
    const float* __restrict__ bias, const float* __restrict__ X,
    float* __restrict__ C, int M, int N, int K)
{
  __shared__ float As[BK][BM + 4];
  __shared__ float Bs[BK][BN + 4];
  const int tid = threadIdx.x;
  const int n0 = blockIdx.x * BN;
  const int m0 = blockIdx.y * BM;
  const int tx = tid & 15;
  const int ty = tid >> 4;
  const int lk  = tid & 15;
  const int lmb = tid >> 4;
  const int lnn = tid & 63;
  const int lkb = tid >> 6;
  float acc[4][4] = {};
  for (int k0 = 0; k0 < K; k0 += BK) {
#pragma unroll
    for (int i = 0; i < 4; ++i) {
      const int m = lmb + 16 * i;
      As[lk][m] = A[(size_t)(m0 + m) * K + (k0 + lk)];
    }
#pragma unroll
    for (int i = 0; i < 4; ++i) {
      const int kk = lkb + 4 * i;
      Bs[kk][lnn] = W[(size_t)(k0 + kk) * N + (n0 + lnn)];
    }
    __syncthreads();
#pragma unroll
    for (int kk = 0; kk < BK; ++kk) {
      float a[4], b[4];
#pragma unroll
      for (int i = 0; i < 4; ++i) a[i] = As[kk][ty * 4 + i];
#pragma unroll
      for (int j = 0; j < 4; ++j) b[j] = Bs[kk][tx * 4 + j];
#pragma unroll
      for (int i = 0; i < 4; ++i)
#pragma unroll
        for (int j = 0; j < 4; ++j)
          acc[i][j] = fmaf(a[i], b[j], acc[i][j]);
    }
    __syncthreads();
  }
#pragma unroll
  for (int i = 0; i < 4; ++i) {
    const int m = m0 + ty * 4 + i;
#pragma unroll
    for (int j = 0; j < 4; ++j) {
      const int n = n0 + tx * 4 + j;
      C[(size_t)m * N + n] = acc[i][j] + bias[n] + X[(size_t)m * N + n];
    }
  }
}

// Per-row: Vx = ||x@Wv||^2, Vf = ||f@Wv||^2 (f64 reduce), closed-form alpha,
// then F <- F * alpha in place. 8 rows per block, thread t owns column k=t.
__global__ __launch_bounds__(256) void k_alpha(
    const float* __restrict__ X, const float* __restrict__ Wv,
    float* __restrict__ F)
{
  const int R = 8;
  __shared__ float xs[R][256];
  __shared__ float fs[R][256];
  __shared__ double part[2][R][4];
  __shared__ float als[R];
  const int tid = threadIdx.x;
  const int row0 = blockIdx.x * R;

#pragma unroll
  for (int r = 0; r < R; ++r) {
    xs[r][tid] = X[(size_t)(row0 + r) * 256 + tid];
    fs[r][tid] = F[(size_t)(row0 + r) * 256 + tid];
  }
  __syncthreads();

  float zx[R] = {}, zf[R] = {};
  for (int n4 = 0; n4 < 64; ++n4) {
    const int n = n4 * 4;
    const float w0 = Wv[(size_t)(n + 0) * 256 + tid];
    const float w1 = Wv[(size_t)(n + 1) * 256 + tid];
    const float w2 = Wv[(size_t)(n + 2) * 256 + tid];
    const float w3 = Wv[(size_t)(n + 3) * 256 + tid];
#pragma unroll
    for (int r = 0; r < R; ++r) {
      const float4 xv = reinterpret_cast<const float4*>(xs[r])[n4];
      const float4 fv = reinterpret_cast<const float4*>(fs[r])[n4];
      zx[r] = fmaf(xv.x, w0, fmaf(xv.y, w1, fmaf(xv.z, w2, fmaf(xv.w, w3, zx[r]))));
      zf[r] = fmaf(fv.x, w0, fmaf(fv.y, w1, fmaf(fv.z, w2, fmaf(fv.w, w3, zf[r]))));
    }
  }

  const int lane = tid & 63;
  const int wv_id = tid >> 6;
#pragma unroll
  for (int r = 0; r < R; ++r) {
    double vx = (double)zx[r] * (double)zx[r];
    double vf = (double)zf[r] * (double)zf[r];
    for (int off = 32; off > 0; off >>= 1) {
      vx += __shfl_down(vx, off, 64);
      vf += __shfl_down(vf, off, 64);
    }
    if (lane == 0) { part[0][r][wv_id] = vx; part[1][r][wv_id] = vf; }
  }
  __syncthreads();

  if (tid < R) {
    const double Vx = part[0][tid][0] + part[0][tid][1] + part[0][tid][2] + part[0][tid][3];
    const double Vf = part[1][tid][0] + part[1][tid][1] + part[1][tid][2] + part[1][tid][3];
    const double tt = 0.99 * Vx;
    float a;
    if (Vf - tt > 0.0)            a = (float)sqrt(tt / Vf);   // Newton limit
    else if (tt - Vf > 1e-4)      a = 0.5f;                    // stuck-bisection case
    else                          a = 1.0f;                    // never masked
    als[tid] = a;
  }
  __syncthreads();

#pragma unroll
  for (int r = 0; r < R; ++r)
    F[(size_t)(row0 + r) * 256 + tid] = fs[r][tid] * als[r];
}

extern "C" void kernel_launch(void* const* d_in, const int* in_sizes, int n_in,
                              void* d_out, int out_size, void* d_ws, size_t ws_size,
                              hipStream_t stream) {
  const float* x  = (const float*)d_in[0];
  const float* W1 = (const float*)d_in[1];
  const float* b1 = (const float*)d_in[2];
  const float* W2 = (const float*)d_in[3];
  const float* b2 = (const float*)d_in[4];
  const float* Wv = (const float*)d_in[5];
  float* out = (float*)d_out;
  float* H = (float*)d_ws;  // 8192*1024 f32 = 33.6 MB scratch

  const int Bm = 8192, Nn = 256, Hh = 1024;
  dim3 blk(256);
  k_gemm_tanh <<<dim3(Hh / BN, Bm / BM), blk, 0, stream>>>(x, W1, b1, H, Bm, Hh, Nn);
  k_gemm_resid<<<dim3(Nn / BN, Bm / BM), blk, 0, stream>>>(H, W2, b2, x, out, Bm, Nn, Hh);
  k_alpha     <<<dim3(Bm / 8), blk, 0, stream>>>(x, Wv, out);
}

// Round 2
// 116.081 us; speedup vs baseline: 1.6610x; 1.6610x over previous
//
#include <hip/hip_runtime.h>
#include <math.h>

typedef __attribute__((ext_vector_type(8))) short bf16x8;
typedef __attribute__((ext_vector_type(4))) float f32x4;

static __device__ __forceinline__ unsigned short f2bf(float f) {
  union { float f; unsigned u; } a; a.f = f;
  unsigned u = a.u;
  unsigned r = u + 0x7FFF + ((u >> 16) & 1);   // RNE
  return (unsigned short)(r >> 16);
}
static __device__ __forceinline__ float bf2f(unsigned short h) {
  union { unsigned u; float f; } a; a.u = ((unsigned)h) << 16;
  return a.f;
}
static __device__ __forceinline__ float tanh_fast(float x) {
  float ax = fabsf(x);
  float e = __expf(-2.0f * ax);
  float t = (1.0f - e) / (1.0f + e);
  t = (ax > 10.0f) ? 1.0f : t;
  return (x < 0.0f) ? -t : t;
}

// WT[n][k] = W[k][n]; split to bf16 hi/lo.  (reads strided but L2-resident, writes coalesced)
__global__ __launch_bounds__(256) void k_split_w(
    const float* __restrict__ W, int Kd, int Nd,
    unsigned short* __restrict__ WT_h, unsigned short* __restrict__ WT_l)
{
  int idx = blockIdx.x * 256 + threadIdx.x;
  int k = idx % Kd, n = idx / Kd;
  if (n >= Nd) return;
  float w = W[(size_t)k * Nd + n];
  unsigned short h = f2bf(w);
  WT_h[(size_t)n * Kd + k] = h;
  WT_l[(size_t)n * Kd + k] = f2bf(w - bf2f(h));
}

// GEMM1: H = tanh(x @ W1 + b1).  M=8192 K=256 N=1024.  BM=128 BN=128 BK=32.
// A = x (f32, split in-kernel), B = W1T hi/lo (pre-split, [N][K] bf16).
// Output written as bf16 hi/lo pair.
__global__ __launch_bounds__(256) void k_gemm1(
    const float* __restrict__ X, const unsigned short* __restrict__ BTh,
    const unsigned short* __restrict__ BTl, const float* __restrict__ bias,
    unsigned short* __restrict__ Hh, unsigned short* __restrict__ Hl)
{
  const int PIT = 40;  // 32 bf16 + 8 pad (80B rows: 2-way bank aliasing, 16B aligned)
  __shared__ __align__(16) unsigned short As_h[128 * PIT], As_l[128 * PIT];
  __shared__ __align__(16) unsigned short Bs_h[128 * PIT], Bs_l[128 * PIT];
  const int t = threadIdx.x;
  const int n0 = blockIdx.x * 128, m0 = blockIdx.y * 128;
  const int l = t & 63, wid = t >> 6;
  const int wr = wid >> 1, wc = wid & 1;           // wave -> 64x64 sub-tile
  const int kk = (l >> 4) * 8;                     // frag k-offset (bf16 units)

  f32x4 acc[4][4] = {};

  for (int k0 = 0; k0 < 256; k0 += 32) {
    // stage A: x tile 128x32 f32 -> hi/lo LDS
#pragma unroll
    for (int i = 0; i < 4; ++i) {
      const int row = (t >> 3) + 32 * i, q = t & 7;
      const float4 v = *reinterpret_cast<const float4*>(&X[(size_t)(m0 + row) * 256 + k0 + q * 4]);
      unsigned short h0 = f2bf(v.x), h1 = f2bf(v.y), h2 = f2bf(v.z), h3 = f2bf(v.w);
      uint2 hp, lp;
      hp.x = (unsigned)h0 | ((unsigned)h1 << 16);
      hp.y = (unsigned)h2 | ((unsigned)h3 << 16);
      unsigned short l0 = f2bf(v.x - bf2f(h0)), l1 = f2bf(v.y - bf2f(h1));
      unsigned short l2 = f2bf(v.z - bf2f(h2)), l3 = f2bf(v.w - bf2f(h3));
      lp.x = (unsigned)l0 | ((unsigned)l1 << 16);
      lp.y = (unsigned)l2 | ((unsigned)l3 << 16);
      *reinterpret_cast<uint2*>(&As_h[row * PIT + q * 4]) = hp;
      *reinterpret_cast<uint2*>(&As_l[row * PIT + q * 4]) = lp;
    }
    // stage B: W1T tile 128x32 bf16, pure 16B copies
#pragma unroll
    for (int cc = 0; cc < 2; ++cc) {
      const int c = 2 * t + cc, n = c >> 2, c4 = c & 3;
      *reinterpret_cast<uint4*>(&Bs_h[n * PIT + c4 * 8]) =
          *reinterpret_cast<const uint4*>(&BTh[(size_t)(n0 + n) * 256 + k0 + c4 * 8]);
      *reinterpret_cast<uint4*>(&Bs_l[n * PIT + c4 * 8]) =
          *reinterpret_cast<const uint4*>(&BTl[(size_t)(n0 + n) * 256 + k0 + c4 * 8]);
    }
    __syncthreads();

    bf16x8 ah[4], al[4], bh[4], bl[4];
#pragma unroll
    for (int i = 0; i < 4; ++i) {
      const int ar = wr * 64 + i * 16 + (l & 15);
      ah[i] = *reinterpret_cast<const bf16x8*>(&As_h[ar * PIT + kk]);
      al[i] = *reinterpret_cast<const bf16x8*>(&As_l[ar * PIT + kk]);
      const int br = wc * 64 + i * 16 + (l & 15);
      bh[i] = *reinterpret_cast<const bf16x8*>(&Bs_h[br * PIT + kk]);
      bl[i] = *reinterpret_cast<const bf16x8*>(&Bs_l[br * PIT + kk]);
    }
#pragma unroll
    for (int i = 0; i < 4; ++i)
#pragma unroll
      for (int j = 0; j < 4; ++j) {
        acc[i][j] = __builtin_amdgcn_mfma_f32_16x16x32_bf16(ah[i], bh[j], acc[i][j], 0, 0, 0);
        acc[i][j] = __builtin_amdgcn_mfma_f32_16x16x32_bf16(ah[i], bl[j], acc[i][j], 0, 0, 0);
        acc[i][j] = __builtin_amdgcn_mfma_f32_16x16x32_bf16(al[i], bh[j], acc[i][j], 0, 0, 0);
      }
    __syncthreads();
  }

#pragma unroll
  for (int i = 0; i < 4; ++i)
#pragma unroll
    for (int j = 0; j < 4; ++j) {
      const int gn = n0 + wc * 64 + j * 16 + (l & 15);
      const float bv = bias[gn];
#pragma unroll
      for (int r = 0; r < 4; ++r) {
        const int gm = m0 + wr * 64 + i * 16 + (l >> 4) * 4 + r;
        const float tv = tanh_fast(acc[i][j][r] + bv);
        const unsigned short th = f2bf(tv);
        Hh[(size_t)gm * 1024 + gn] = th;
        Hl[(size_t)gm * 1024 + gn] = f2bf(tv - bf2f(th));
      }
    }
}

// GEMM2: out = H @ W2 + b2 + x.  M=8192 K=1024 N=256.  BM=64 BN=64 BK=32.
__global__ __launch_bounds__(256) void k_gemm2(
    const unsigned short* __restrict__ Ah, const unsigned short* __restrict__ Al,
    const unsigned short* __restrict__ BTh, const unsigned short* __restrict__ BTl,
    const float* __restrict__ bias, const float* __restrict__ X,
    float* __restrict__ OUT)
{
  const int PIT = 40;
  __shared__ __align__(16) unsigned short As_h[64 * PIT], As_l[64 * PIT];
  __shared__ __align__(16) unsigned short Bs_h[64 * PIT], Bs_l[64 * PIT];
  const int t = threadIdx.x;
  const int n0 = blockIdx.x * 64, m0 = blockIdx.y * 64;
  const int l = t & 63, wid = t >> 6;
  const int wr = wid >> 1, wc = wid & 1;           // wave -> 32x32 sub-tile
  const int kk = (l >> 4) * 8;

  f32x4 acc[2][2] = {};
  const int row = t >> 2, c4 = t & 3;

  for (int k0 = 0; k0 < 1024; k0 += 32) {
    *reinterpret_cast<uint4*>(&As_h[row * PIT + c4 * 8]) =
        *reinterpret_cast<const uint4*>(&Ah[(size_t)(m0 + row) * 1024 + k0 + c4 * 8]);
    *reinterpret_cast<uint4*>(&As_l[row * PIT + c4 * 8]) =
        *reinterpret_cast<const uint4*>(&Al[(size_t)(m0 + row) * 1024 + k0 + c4 * 8]);
    *reinterpret_cast<uint4*>(&Bs_h[row * PIT + c4 * 8]) =
        *reinterpret_cast<const uint4*>(&BTh[(size_t)(n0 + row) * 1024 + k0 + c4 * 8]);
    *reinterpret_cast<uint4*>(&Bs_l[row * PIT + c4 * 8]) =
        *reinterpret_cast<const uint4*>(&BTl[(size_t)(n0 + row) * 1024 + k0 + c4 * 8]);
    __syncthreads();

    bf16x8 ah[2], al[2], bh[2], bl[2];
#pragma unroll
    for (int i = 0; i < 2; ++i) {
      const int ar = wr * 32 + i * 16 + (l & 15);
      ah[i] = *reinterpret_cast<const bf16x8*>(&As_h[ar * PIT + kk]);
      al[i] = *reinterpret_cast<const bf16x8*>(&As_l[ar * PIT + kk]);
      const int br = wc * 32 + i * 16 + (l & 15);
      bh[i] = *reinterpret_cast<const bf16x8*>(&Bs_h[br * PIT + kk]);
      bl[i] = *reinterpret_cast<const bf16x8*>(&Bs_l[br * PIT + kk]);
    }
#pragma unroll
    for (int i = 0; i < 2; ++i)
#pragma unroll
      for (int j = 0; j < 2; ++j) {
        acc[i][j] = __builtin_amdgcn_mfma_f32_16x16x32_bf16(ah[i], bh[j], acc[i][j], 0, 0, 0);
        acc[i][j] = __builtin_amdgcn_mfma_f32_16x16x32_bf16(ah[i], bl[j], acc[i][j], 0, 0, 0);
        acc[i][j] = __builtin_amdgcn_mfma_f32_16x16x32_bf16(al[i], bh[j], acc[i][j], 0, 0, 0);
      }
    __syncthreads();
  }

#pragma unroll
  for (int i = 0; i < 2; ++i)
#pragma unroll
    for (int j = 0; j < 2; ++j) {
      const int gn = n0 + wc * 32 + j * 16 + (l & 15);
      const float bv = bias[gn];
#pragma unroll
      for (int r = 0; r < 4; ++r) {
        const int gm = m0 + wr * 32 + i * 16 + (l >> 4) * 4 + r;
        OUT[(size_t)gm * 256 + gn] = acc[i][j][r] + bv + X[(size_t)gm * 256 + gn];
      }
    }
}

// Per-row closed-form alpha from V(x), V(f); scale F in place.  (unchanged)
__global__ __launch_bounds__(256) void k_alpha(
    const float* __restrict__ X, const float* __restrict__ Wv,
    float* __restrict__ F)
{
  const int R = 8;
  __shared__ float xs[R][256];
  __shared__ float fs[R][256];
  __shared__ double part[2][R][4];
  __shared__ float als[R];
  const int tid = threadIdx.x;
  const int row0 = blockIdx.x * R;

#pragma unroll
  for (int r = 0; r < R; ++r) {
    xs[r][tid] = X[(size_t)(row0 + r) * 256 + tid];
    fs[r][tid] = F[(size_t)(row0 + r) * 256 + tid];
  }
  __syncthreads();

  float zx[R] = {}, zf[R] = {};
  for (int n4 = 0; n4 < 64; ++n4) {
    const int n = n4 * 4;
    const float w0 = Wv[(size_t)(n + 0) * 256 + tid];
    const float w1 = Wv[(size_t)(n + 1) * 256 + tid];
    const float w2 = Wv[(size_t)(n + 2) * 256 + tid];
    const float w3 = Wv[(size_t)(n + 3) * 256 + tid];
#pragma unroll
    for (int r = 0; r < R; ++r) {
      const float4 xv = reinterpret_cast<const float4*>(xs[r])[n4];
      const float4 fv = reinterpret_cast<const float4*>(fs[r])[n4];
      zx[r] = fmaf(xv.x, w0, fmaf(xv.y, w1, fmaf(xv.z, w2, fmaf(xv.w, w3, zx[r]))));
      zf[r] = fmaf(fv.x, w0, fmaf(fv.y, w1, fmaf(fv.z, w2, fmaf(fv.w, w3, zf[r]))));
    }
  }

  const int lane = tid & 63;
  const int wv_id = tid >> 6;
#pragma unroll
  for (int r = 0; r < R; ++r) {
    double vx = (double)zx[r] * (double)zx[r];
    double vf = (double)zf[r] * (double)zf[r];
    for (int off = 32; off > 0; off >>= 1) {
      vx += __shfl_down(vx, off, 64);
      vf += __shfl_down(vf, off, 64);
    }
    if (lane == 0) { part[0][r][wv_id] = vx; part[1][r][wv_id] = vf; }
  }
  __syncthreads();

  if (tid < R) {
    const double Vx = part[0][tid][0] + part[0][tid][1] + part[0][tid][2] + part[0][tid][3];
    const double Vf = part[1][tid][0] + part[1][tid][1] + part[1][tid][2] + part[1][tid][3];
    const double tt = 0.99 * Vx;
    float a;
    if (Vf - tt > 0.0)            a = (float)sqrt(tt / Vf);   // Newton limit
    else if (tt - Vf > 1e-4)      a = 0.5f;                    // stuck-bisection case
    else                          a = 1.0f;                    // never masked
    als[tid] = a;
  }
  __syncthreads();

#pragma unroll
  for (int r = 0; r < R; ++r)
    F[(size_t)(row0 + r) * 256 + tid] = fs[r][tid] * als[r];
}

extern "C" void kernel_launch(void* const* d_in, const int* in_sizes, int n_in,
                              void* d_out, int out_size, void* d_ws, size_t ws_size,
                              hipStream_t stream) {
  const float* x  = (const float*)d_in[0];
  const float* W1 = (const float*)d_in[1];
  const float* b1 = (const float*)d_in[2];
  const float* W2 = (const float*)d_in[3];
  const float* b2 = (const float*)d_in[4];
  const float* Wv = (const float*)d_in[5];
  float* out = (float*)d_out;

  // workspace layout (bytes)
  char* ws = (char*)d_ws;
  unsigned short* Hh   = (unsigned short*)(ws);                         // 16.8 MB
  unsigned short* Hl   = (unsigned short*)(ws + 16777216);              // 16.8 MB
  unsigned short* W1Th = (unsigned short*)(ws + 33554432);              // 0.5 MB
  unsigned short* W1Tl = (unsigned short*)(ws + 33554432 + 524288);
  unsigned short* W2Th = (unsigned short*)(ws + 33554432 + 2 * 524288);
  unsigned short* W2Tl = (unsigned short*)(ws + 33554432 + 3 * 524288); // total 35.7 MB

  dim3 blk(256);
  // W1: [K=256][N=1024] -> W1T [1024][256]; W2: [K=1024][N=256] -> W2T [256][1024]
  k_split_w<<<dim3(256 * 1024 / 256), blk, 0, stream>>>(W1, 256, 1024, W1Th, W1Tl);
  k_split_w<<<dim3(1024 * 256 / 256), blk, 0, stream>>>(W2, 1024, 256, W2Th, W2Tl);

  k_gemm1<<<dim3(1024 / 128, 8192 / 128), blk, 0, stream>>>(x, W1Th, W1Tl, b1, Hh, Hl);
  k_gemm2<<<dim3(256 / 64, 8192 / 64), blk, 0, stream>>>(Hh, Hl, W2Th, W2Tl, b2, x, out);
  k_alpha<<<dim3(8192 / 8), blk, 0, stream>>>(x, Wv, out);
}

// Round 3
// 90.282 us; speedup vs baseline: 2.1356x; 1.2858x over previous
//
#include <hip/hip_runtime.h>
#include <math.h>

typedef __attribute__((ext_vector_type(8))) short bf16x8;
typedef __attribute__((ext_vector_type(4))) float f32x4;

static __device__ __forceinline__ unsigned short f2bf(float f) {
  union { float f; unsigned u; } a; a.f = f;
  unsigned u = a.u;
  unsigned r = u + 0x7FFF + ((u >> 16) & 1);   // RNE
  return (unsigned short)(r >> 16);
}
static __device__ __forceinline__ float bf2f(unsigned short h) {
  union { unsigned u; float f; } a; a.u = ((unsigned)h) << 16;
  return a.f;
}
static __device__ __forceinline__ float tanh_fast(float x) {
  float ax = fabsf(x);
  float e = __expf(-2.0f * ax);
  float t = (1.0f - e) / (1.0f + e);
  t = (ax > 10.0f) ? 1.0f : t;
  return (x < 0.0f) ? -t : t;
}

// WT[n][k] = W[k][n]; split to bf16 hi/lo.
__global__ __launch_bounds__(256) void k_split_w(
    const float* __restrict__ W, int Kd, int Nd,
    unsigned short* __restrict__ WT_h, unsigned short* __restrict__ WT_l)
{
  int idx = blockIdx.x * 256 + threadIdx.x;
  int k = idx % Kd, n = idx / Kd;
  if (n >= Nd) return;
  float w = W[(size_t)k * Nd + n];
  unsigned short h = f2bf(w);
  WT_h[(size_t)n * Kd + k] = h;
  WT_l[(size_t)n * Kd + k] = f2bf(w - bf2f(h));
}

// GEMM1: H = tanh(x @ W1 + b1).  M=8192 K=256 N=1024.  BM=128 BN=128 BK=32.
__global__ __launch_bounds__(256) void k_gemm1(
    const float* __restrict__ X, const unsigned short* __restrict__ BTh,
    const unsigned short* __restrict__ BTl, const float* __restrict__ bias,
    unsigned short* __restrict__ Hh, unsigned short* __restrict__ Hl)
{
  const int PIT = 40;
  __shared__ __align__(16) unsigned short As_h[128 * PIT], As_l[128 * PIT];
  __shared__ __align__(16) unsigned short Bs_h[128 * PIT], Bs_l[128 * PIT];
  const int t = threadIdx.x;
  const int n0 = blockIdx.x * 128, m0 = blockIdx.y * 128;
  const int l = t & 63, wid = t >> 6;
  const int wr = wid >> 1, wc = wid & 1;
  const int kk = (l >> 4) * 8;

  f32x4 acc[4][4] = {};

  for (int k0 = 0; k0 < 256; k0 += 32) {
#pragma unroll
    for (int i = 0; i < 4; ++i) {
      const int row = (t >> 3) + 32 * i, q = t & 7;
      const float4 v = *reinterpret_cast<const float4*>(&X[(size_t)(m0 + row) * 256 + k0 + q * 4]);
      unsigned short h0 = f2bf(v.x), h1 = f2bf(v.y), h2 = f2bf(v.z), h3 = f2bf(v.w);
      uint2 hp, lp;
      hp.x = (unsigned)h0 | ((unsigned)h1 << 16);
      hp.y = (unsigned)h2 | ((unsigned)h3 << 16);
      unsigned short l0 = f2bf(v.x - bf2f(h0)), l1 = f2bf(v.y - bf2f(h1));
      unsigned short l2 = f2bf(v.z - bf2f(h2)), l3 = f2bf(v.w - bf2f(h3));
      lp.x = (unsigned)l0 | ((unsigned)l1 << 16);
      lp.y = (unsigned)l2 | ((unsigned)l3 << 16);
      *reinterpret_cast<uint2*>(&As_h[row * PIT + q * 4]) = hp;
      *reinterpret_cast<uint2*>(&As_l[row * PIT + q * 4]) = lp;
    }
#pragma unroll
    for (int cc = 0; cc < 2; ++cc) {
      const int c = 2 * t + cc, n = c >> 2, c4 = c & 3;
      *reinterpret_cast<uint4*>(&Bs_h[n * PIT + c4 * 8]) =
          *reinterpret_cast<const uint4*>(&BTh[(size_t)(n0 + n) * 256 + k0 + c4 * 8]);
      *reinterpret_cast<uint4*>(&Bs_l[n * PIT + c4 * 8]) =
          *reinterpret_cast<const uint4*>(&BTl[(size_t)(n0 + n) * 256 + k0 + c4 * 8]);
    }
    __syncthreads();

    bf16x8 ah[4], al[4], bh[4], bl[4];
#pragma unroll
    for (int i = 0; i < 4; ++i) {
      const int ar = wr * 64 + i * 16 + (l & 15);
      ah[i] = *reinterpret_cast<const bf16x8*>(&As_h[ar * PIT + kk]);
      al[i] = *reinterpret_cast<const bf16x8*>(&As_l[ar * PIT + kk]);
      const int br = wc * 64 + i * 16 + (l & 15);
      bh[i] = *reinterpret_cast<const bf16x8*>(&Bs_h[br * PIT + kk]);
      bl[i] = *reinterpret_cast<const bf16x8*>(&Bs_l[br * PIT + kk]);
    }
#pragma unroll
    for (int i = 0; i < 4; ++i)
#pragma unroll
      for (int j = 0; j < 4; ++j) {
        acc[i][j] = __builtin_amdgcn_mfma_f32_16x16x32_bf16(ah[i], bh[j], acc[i][j], 0, 0, 0);
        acc[i][j] = __builtin_amdgcn_mfma_f32_16x16x32_bf16(ah[i], bl[j], acc[i][j], 0, 0, 0);
        acc[i][j] = __builtin_amdgcn_mfma_f32_16x16x32_bf16(al[i], bh[j], acc[i][j], 0, 0, 0);
      }
    __syncthreads();
  }

#pragma unroll
  for (int i = 0; i < 4; ++i)
#pragma unroll
    for (int j = 0; j < 4; ++j) {
      const int gn = n0 + wc * 64 + j * 16 + (l & 15);
      const float bv = bias[gn];
#pragma unroll
      for (int r = 0; r < 4; ++r) {
        const int gm = m0 + wr * 64 + i * 16 + (l >> 4) * 4 + r;
        const float tv = tanh_fast(acc[i][j][r] + bv);
        const unsigned short th = f2bf(tv);
        Hh[(size_t)gm * 1024 + gn] = th;
        Hl[(size_t)gm * 1024 + gn] = f2bf(tv - bf2f(th));
      }
    }
}

// GEMM2: out = H @ W2 + b2 + x.  M=8192 K=1024 N=256.  BM=64 BN=64 BK=32.
__global__ __launch_bounds__(256) void k_gemm2(
    const unsigned short* __restrict__ Ah, const unsigned short* __restrict__ Al,
    const unsigned short* __restrict__ BTh, const unsigned short* __restrict__ BTl,
    const float* __restrict__ bias, const float* __restrict__ X,
    float* __restrict__ OUT)
{
  const int PIT = 40;
  __shared__ __align__(16) unsigned short As_h[64 * PIT], As_l[64 * PIT];
  __shared__ __align__(16) unsigned short Bs_h[64 * PIT], Bs_l[64 * PIT];
  const int t = threadIdx.x;
  const int n0 = blockIdx.x * 64, m0 = blockIdx.y * 64;
  const int l = t & 63, wid = t >> 6;
  const int wr = wid >> 1, wc = wid & 1;
  const int kk = (l >> 4) * 8;

  f32x4 acc[2][2] = {};
  const int row = t >> 2, c4 = t & 3;

  for (int k0 = 0; k0 < 1024; k0 += 32) {
    *reinterpret_cast<uint4*>(&As_h[row * PIT + c4 * 8]) =
        *reinterpret_cast<const uint4*>(&Ah[(size_t)(m0 + row) * 1024 + k0 + c4 * 8]);
    *reinterpret_cast<uint4*>(&As_l[row * PIT + c4 * 8]) =
        *reinterpret_cast<const uint4*>(&Al[(size_t)(m0 + row) * 1024 + k0 + c4 * 8]);
    *reinterpret_cast<uint4*>(&Bs_h[row * PIT + c4 * 8]) =
        *reinterpret_cast<const uint4*>(&BTh[(size_t)(n0 + row) * 1024 + k0 + c4 * 8]);
    *reinterpret_cast<uint4*>(&Bs_l[row * PIT + c4 * 8]) =
        *reinterpret_cast<const uint4*>(&BTl[(size_t)(n0 + row) * 1024 + k0 + c4 * 8]);
    __syncthreads();

    bf16x8 ah[2], al[2], bh[2], bl[2];
#pragma unroll
    for (int i = 0; i < 2; ++i) {
      const int ar = wr * 32 + i * 16 + (l & 15);
      ah[i] = *reinterpret_cast<const bf16x8*>(&As_h[ar * PIT + kk]);
      al[i] = *reinterpret_cast<const bf16x8*>(&As_l[ar * PIT + kk]);
      const int br = wc * 32 + i * 16 + (l & 15);
      bh[i] = *reinterpret_cast<const bf16x8*>(&Bs_h[br * PIT + kk]);
      bl[i] = *reinterpret_cast<const bf16x8*>(&Bs_l[br * PIT + kk]);
    }
#pragma unroll
    for (int i = 0; i < 2; ++i)
#pragma unroll
      for (int j = 0; j < 2; ++j) {
        acc[i][j] = __builtin_amdgcn_mfma_f32_16x16x32_bf16(ah[i], bh[j], acc[i][j], 0, 0, 0);
        acc[i][j] = __builtin_amdgcn_mfma_f32_16x16x32_bf16(ah[i], bl[j], acc[i][j], 0, 0, 0);
        acc[i][j] = __builtin_amdgcn_mfma_f32_16x16x32_bf16(al[i], bh[j], acc[i][j], 0, 0, 0);
      }
    __syncthreads();
  }

#pragma unroll
  for (int i = 0; i < 2; ++i)
#pragma unroll
    for (int j = 0; j < 2; ++j) {
      const int gn = n0 + wc * 32 + j * 16 + (l & 15);
      const float bv = bias[gn];
#pragma unroll
      for (int r = 0; r < 4; ++r) {
        const int gm = m0 + wr * 32 + i * 16 + (l >> 4) * 4 + r;
        OUT[(size_t)gm * 256 + gn] = acc[i][j][r] + bv + X[(size_t)gm * 256 + gn];
      }
    }
}

// Fused: Z = [x;f] @ Wv via MFMA, V = row-sum(Z^2) in f64, closed-form alpha,
// F *= alpha (F values kept in staging registers).  16 output rows per block.
// LDS A-tile [32 rows][256 bf16], stride 512B, XOR-swizzled byte^=(row&7)<<4.
__global__ __launch_bounds__(256) void k_valpha(
    const float* __restrict__ X,
    const unsigned short* __restrict__ WvTh, const unsigned short* __restrict__ WvTl,
    float* __restrict__ F)
{
  __shared__ __align__(16) unsigned short Ah[32 * 256];
  __shared__ __align__(16) unsigned short Al[32 * 256];
  __shared__ double part[2][16][4];
  __shared__ float als[16];
  const int t = threadIdx.x;
  const int r0 = blockIdx.x * 16;
  const int l = t & 63, w = t >> 6;

  // stage: A-rows 0..15 = x rows, 16..31 = f rows; keep f float4s in regs
  const int srow = t >> 3;     // 0..31
  const int q = t & 7;
  float4 fv[8];
  {
    const float* src = (srow < 16) ? &X[(size_t)(r0 + srow) * 256]
                                   : &F[(size_t)(r0 + srow - 16) * 256];
#pragma unroll
    for (int i = 0; i < 8; ++i) {
      const float4 v = *reinterpret_cast<const float4*>(&src[(q * 8 + i) * 4]);
      fv[i] = v;
      const unsigned short h0 = f2bf(v.x), h1 = f2bf(v.y), h2 = f2bf(v.z), h3 = f2bf(v.w);
      uint2 hp, lp;
      hp.x = (unsigned)h0 | ((unsigned)h1 << 16);
      hp.y = (unsigned)h2 | ((unsigned)h3 << 16);
      lp.x = (unsigned)f2bf(v.x - bf2f(h0)) | ((unsigned)f2bf(v.y - bf2f(h1)) << 16);
      lp.y = (unsigned)f2bf(v.z - bf2f(h2)) | ((unsigned)f2bf(v.w - bf2f(h3)) << 16);
      const unsigned byte = (unsigned)(srow * 512 + (q * 8 + i) * 8) ^ ((srow & 7) << 4);
      *reinterpret_cast<uint2*>(((char*)Ah) + byte) = hp;
      *reinterpret_cast<uint2*>(((char*)Al) + byte) = lp;
    }
  }
  __syncthreads();

  // MFMA: wave w owns cols [w*64, w*64+64)
  const int nb = w * 64;
  const int c = l & 15, g = l >> 4;
  double vs[2][4] = {};
#pragma unroll
  for (int nf = 0; nf < 4; ++nf) {
    const int col = nb + nf * 16 + c;
    f32x4 acc0 = {}, acc1 = {};
#pragma unroll
    for (int ks = 0; ks < 8; ++ks) {
      const int kof = ks * 32 + g * 8;   // bf16 units
      const bf16x8 bh = *reinterpret_cast<const bf16x8*>(&WvTh[col * 256 + kof]);
      const bf16x8 bl = *reinterpret_cast<const bf16x8*>(&WvTl[col * 256 + kof]);
      const unsigned ab0 = (unsigned)(c * 512 + kof * 2) ^ ((c & 7) << 4);
      const unsigned ab1 = (unsigned)((c + 16) * 512 + kof * 2) ^ ((c & 7) << 4);
      const bf16x8 a0h = *reinterpret_cast<const bf16x8*>(((char*)Ah) + ab0);
      const bf16x8 a0l = *reinterpret_cast<const bf16x8*>(((char*)Al) + ab0);
      const bf16x8 a1h = *reinterpret_cast<const bf16x8*>(((char*)Ah) + ab1);
      const bf16x8 a1l = *reinterpret_cast<const bf16x8*>(((char*)Al) + ab1);
      acc0 = __builtin_amdgcn_mfma_f32_16x16x32_bf16(a0h, bh, acc0, 0, 0, 0);
      acc0 = __builtin_amdgcn_mfma_f32_16x16x32_bf16(a0h, bl, acc0, 0, 0, 0);
      acc0 = __builtin_amdgcn_mfma_f32_16x16x32_bf16(a0l, bh, acc0, 0, 0, 0);
      acc1 = __builtin_amdgcn_mfma_f32_16x16x32_bf16(a1h, bh, acc1, 0, 0, 0);
      acc1 = __builtin_amdgcn_mfma_f32_16x16x32_bf16(a1h, bl, acc1, 0, 0, 0);
      acc1 = __builtin_amdgcn_mfma_f32_16x16x32_bf16(a1l, bh, acc1, 0, 0, 0);
    }
#pragma unroll
    for (int r = 0; r < 4; ++r) {
      vs[0][r] += (double)acc0[r] * (double)acc0[r];
      vs[1][r] += (double)acc1[r] * (double)acc1[r];
    }
  }

  // reduce over the 16 C-columns (lanes sharing g)
#pragma unroll
  for (int s = 0; s < 2; ++s)
#pragma unroll
    for (int r = 0; r < 4; ++r) {
      double v = vs[s][r];
      v += __shfl_xor(v, 1);
      v += __shfl_xor(v, 2);
      v += __shfl_xor(v, 4);
      v += __shfl_xor(v, 8);
      vs[s][r] = v;
    }
  if (c == 0) {
#pragma unroll
    for (int r = 0; r < 4; ++r) {
      part[0][g * 4 + r][w] = vs[0][r];
      part[1][g * 4 + r][w] = vs[1][r];
    }
  }
  __syncthreads();

  if (t < 16) {
    const double Vx = part[0][t][0] + part[0][t][1] + part[0][t][2] + part[0][t][3];
    const double Vf = part[1][t][0] + part[1][t][1] + part[1][t][2] + part[1][t][3];
    const double tt = 0.99 * Vx;
    float a;
    if (Vf - tt > 0.0)        a = (float)sqrt(tt / Vf);   // Newton limit
    else if (tt - Vf > 1e-4)  a = 0.5f;                   // stuck-bisection case
    else                      a = 1.0f;                   // never masked
    als[t] = a;
  }
  __syncthreads();

  if (t >= 128) {
    const int row = (t >> 3) - 16;
    const float a = als[row];
    float* dst = &F[(size_t)(r0 + row) * 256];
#pragma unroll
    for (int i = 0; i < 8; ++i) {
      float4 v = fv[i];
      v.x *= a; v.y *= a; v.z *= a; v.w *= a;
      *reinterpret_cast<float4*>(&dst[(q * 8 + i) * 4]) = v;
    }
  }
}

extern "C" void kernel_launch(void* const* d_in, const int* in_sizes, int n_in,
                              void* d_out, int out_size, void* d_ws, size_t ws_size,
                              hipStream_t stream) {
  const float* x  = (const float*)d_in[0];
  const float* W1 = (const float*)d_in[1];
  const float* b1 = (const float*)d_in[2];
  const float* W2 = (const float*)d_in[3];
  const float* b2 = (const float*)d_in[4];
  const float* Wv = (const float*)d_in[5];
  float* out = (float*)d_out;

  char* ws = (char*)d_ws;
  unsigned short* Hh   = (unsigned short*)(ws);                          // 16.8 MB
  unsigned short* Hl   = (unsigned short*)(ws + 16777216);               // 16.8 MB
  unsigned short* W1Th = (unsigned short*)(ws + 33554432);
  unsigned short* W1Tl = (unsigned short*)(ws + 33554432 + 524288);
  unsigned short* W2Th = (unsigned short*)(ws + 33554432 + 2 * 524288);
  unsigned short* W2Tl = (unsigned short*)(ws + 33554432 + 3 * 524288);
  unsigned short* WvTh = (unsigned short*)(ws + 33554432 + 4 * 524288);
  unsigned short* WvTl = (unsigned short*)(ws + 33554432 + 4 * 524288 + 131072);

  dim3 blk(256);
  k_split_w<<<dim3(256 * 1024 / 256), blk, 0, stream>>>(W1, 256, 1024, W1Th, W1Tl);
  k_split_w<<<dim3(1024 * 256 / 256), blk, 0, stream>>>(W2, 1024, 256, W2Th, W2Tl);
  k_split_w<<<dim3(256 * 256 / 256),  blk, 0, stream>>>(Wv, 256, 256,  WvTh, WvTl);

  k_gemm1 <<<dim3(1024 / 128, 8192 / 128), blk, 0, stream>>>(x, W1Th, W1Tl, b1, Hh, Hl);
  k_gemm2 <<<dim3(256 / 64, 8192 / 64), blk, 0, stream>>>(Hh, Hl, W2Th, W2Tl, b2, x, out);
  k_valpha<<<dim3(8192 / 16), blk, 0, stream>>>(x, WvTh, WvTl, out);
}

// Round 4
// 82.009 us; speedup vs baseline: 2.3510x; 1.1009x over previous
//
#include <hip/hip_runtime.h>
#include <math.h>

typedef __attribute__((ext_vector_type(8))) short bf16x8;
typedef __attribute__((ext_vector_type(4))) float f32x4;

static __device__ __forceinline__ unsigned short f2bf(float f) {
  union { float f; unsigned u; } a; a.f = f;
  unsigned u = a.u;
  unsigned r = u + 0x7FFF + ((u >> 16) & 1);   // RNE
  return (unsigned short)(r >> 16);
}
static __device__ __forceinline__ float bf2f(unsigned short h) {
  union { unsigned u; float f; } a; a.u = ((unsigned)h) << 16;
  return a.f;
}
static __device__ __forceinline__ float tanh_fast(float x) {
  float ax = fabsf(x);
  float e = __expf(-2.0f * ax);
  float t = (1.0f - e) / (1.0f + e);
  t = (ax > 10.0f) ? 1.0f : t;
  return (x < 0.0f) ? -t : t;
}

// All three weight transpose+splits in one launch.
// W1: [256][1024] -> W1T[1024][256]; W2: [1024][256] -> W2T[256][1024]; Wv: [256][256].
__global__ __launch_bounds__(256) void k_split_all(
    const float* __restrict__ W1, const float* __restrict__ W2, const float* __restrict__ Wv,
    unsigned short* __restrict__ W1Th, unsigned short* __restrict__ W1Tl,
    unsigned short* __restrict__ W2Th, unsigned short* __restrict__ W2Tl,
    unsigned short* __restrict__ WvTh, unsigned short* __restrict__ WvTl)
{
  const int b = blockIdx.x;
  const float* W; unsigned short *Th, *Tl; int Kd, Nd, base;
  if (b < 1024)      { W = W1; Th = W1Th; Tl = W1Tl; Kd = 256;  Nd = 1024; base = 0; }
  else if (b < 2048) { W = W2; Th = W2Th; Tl = W2Tl; Kd = 1024; Nd = 256;  base = 1024; }
  else               { W = Wv; Th = WvTh; Tl = WvTl; Kd = 256;  Nd = 256;  base = 2048; }
  const int idx = (b - base) * 256 + threadIdx.x;
  const int k = idx % Kd, n = idx / Kd;
  const float w = W[(size_t)k * Nd + n];
  const unsigned short h = f2bf(w);
  Th[(size_t)n * Kd + k] = h;
  Tl[(size_t)n * Kd + k] = f2bf(w - bf2f(h));
}

// GEMM1: H = tanh(x @ W1 + b1).  M=8192 K=256 N=1024.  BM=128 BN=128 BK=32.
__global__ __launch_bounds__(256) void k_gemm1(
    const float* __restrict__ X, const unsigned short* __restrict__ BTh,
    const unsigned short* __restrict__ BTl, const float* __restrict__ bias,
    unsigned short* __restrict__ Hh, unsigned short* __restrict__ Hl)
{
  const int PIT = 40;
  __shared__ __align__(16) unsigned short As_h[128 * PIT], As_l[128 * PIT];
  __shared__ __align__(16) unsigned short Bs_h[128 * PIT], Bs_l[128 * PIT];
  const int t = threadIdx.x;
  const int n0 = blockIdx.x * 128, m0 = blockIdx.y * 128;
  const int l = t & 63, wid = t >> 6;
  const int wr = wid >> 1, wc = wid & 1;
  const int kk = (l >> 4) * 8;

  f32x4 acc[4][4] = {};

  for (int k0 = 0; k0 < 256; k0 += 32) {
#pragma unroll
    for (int i = 0; i < 4; ++i) {
      const int row = (t >> 3) + 32 * i, q = t & 7;
      const float4 v = *reinterpret_cast<const float4*>(&X[(size_t)(m0 + row) * 256 + k0 + q * 4]);
      unsigned short h0 = f2bf(v.x), h1 = f2bf(v.y), h2 = f2bf(v.z), h3 = f2bf(v.w);
      uint2 hp, lp;
      hp.x = (unsigned)h0 | ((unsigned)h1 << 16);
      hp.y = (unsigned)h2 | ((unsigned)h3 << 16);
      unsigned short l0 = f2bf(v.x - bf2f(h0)), l1 = f2bf(v.y - bf2f(h1));
      unsigned short l2 = f2bf(v.z - bf2f(h2)), l3 = f2bf(v.w - bf2f(h3));
      lp.x = (unsigned)l0 | ((unsigned)l1 << 16);
      lp.y = (unsigned)l2 | ((unsigned)l3 << 16);
      *reinterpret_cast<uint2*>(&As_h[row * PIT + q * 4]) = hp;
      *reinterpret_cast<uint2*>(&As_l[row * PIT + q * 4]) = lp;
    }
#pragma unroll
    for (int cc = 0; cc < 2; ++cc) {
      const int c = 2 * t + cc, n = c >> 2, c4 = c & 3;
      *reinterpret_cast<uint4*>(&Bs_h[n * PIT + c4 * 8]) =
          *reinterpret_cast<const uint4*>(&BTh[(size_t)(n0 + n) * 256 + k0 + c4 * 8]);
      *reinterpret_cast<uint4*>(&Bs_l[n * PIT + c4 * 8]) =
          *reinterpret_cast<const uint4*>(&BTl[(size_t)(n0 + n) * 256 + k0 + c4 * 8]);
    }
    __syncthreads();

    bf16x8 ah[4], al[4], bh[4], bl[4];
#pragma unroll
    for (int i = 0; i < 4; ++i) {
      const int ar = wr * 64 + i * 16 + (l & 15);
      ah[i] = *reinterpret_cast<const bf16x8*>(&As_h[ar * PIT + kk]);
      al[i] = *reinterpret_cast<const bf16x8*>(&As_l[ar * PIT + kk]);
      const int br = wc * 64 + i * 16 + (l & 15);
      bh[i] = *reinterpret_cast<const bf16x8*>(&Bs_h[br * PIT + kk]);
      bl[i] = *reinterpret_cast<const bf16x8*>(&Bs_l[br * PIT + kk]);
    }
#pragma unroll
    for (int i = 0; i < 4; ++i)
#pragma unroll
      for (int j = 0; j < 4; ++j) {
        acc[i][j] = __builtin_amdgcn_mfma_f32_16x16x32_bf16(ah[i], bh[j], acc[i][j], 0, 0, 0);
        acc[i][j] = __builtin_amdgcn_mfma_f32_16x16x32_bf16(ah[i], bl[j], acc[i][j], 0, 0, 0);
        acc[i][j] = __builtin_amdgcn_mfma_f32_16x16x32_bf16(al[i], bh[j], acc[i][j], 0, 0, 0);
      }
    __syncthreads();
  }

#pragma unroll
  for (int i = 0; i < 4; ++i)
#pragma unroll
    for (int j = 0; j < 4; ++j) {
      const int gn = n0 + wc * 64 + j * 16 + (l & 15);
      const float bv = bias[gn];
#pragma unroll
      for (int r = 0; r < 4; ++r) {
        const int gm = m0 + wr * 64 + i * 16 + (l >> 4) * 4 + r;
        const float tv = tanh_fast(acc[i][j][r] + bv);
        const unsigned short th = f2bf(tv);
        Hh[(size_t)gm * 1024 + gn] = th;
        Hl[(size_t)gm * 1024 + gn] = f2bf(tv - bf2f(th));
      }
    }
}

// GEMM2: out = H @ W2 + b2 + x.  M=8192 K=1024 N=256.  BM=64 BN=64 BK=32.
__global__ __launch_bounds__(256) void k_gemm2(
    const unsigned short* __restrict__ Ah, const unsigned short* __restrict__ Al,
    const unsigned short* __restrict__ BTh, const unsigned short* __restrict__ BTl,
    const float* __restrict__ bias, const float* __restrict__ X,
    float* __restrict__ OUT)
{
  const int PIT = 40;
  __shared__ __align__(16) unsigned short As_h[64 * PIT], As_l[64 * PIT];
  __shared__ __align__(16) unsigned short Bs_h[64 * PIT], Bs_l[64 * PIT];
  const int t = threadIdx.x;
  const int n0 = blockIdx.x * 64, m0 = blockIdx.y * 64;
  const int l = t & 63, wid = t >> 6;
  const int wr = wid >> 1, wc = wid & 1;
  const int kk = (l >> 4) * 8;

  f32x4 acc[2][2] = {};
  const int row = t >> 2, c4 = t & 3;

  for (int k0 = 0; k0 < 1024; k0 += 32) {
    *reinterpret_cast<uint4*>(&As_h[row * PIT + c4 * 8]) =
        *reinterpret_cast<const uint4*>(&Ah[(size_t)(m0 + row) * 1024 + k0 + c4 * 8]);
    *reinterpret_cast<uint4*>(&As_l[row * PIT + c4 * 8]) =
        *reinterpret_cast<const uint4*>(&Al[(size_t)(m0 + row) * 1024 + k0 + c4 * 8]);
    *reinterpret_cast<uint4*>(&Bs_h[row * PIT + c4 * 8]) =
        *reinterpret_cast<const uint4*>(&BTh[(size_t)(n0 + row) * 1024 + k0 + c4 * 8]);
    *reinterpret_cast<uint4*>(&Bs_l[row * PIT + c4 * 8]) =
        *reinterpret_cast<const uint4*>(&BTl[(size_t)(n0 + row) * 1024 + k0 + c4 * 8]);
    __syncthreads();

    bf16x8 ah[2], al[2], bh[2], bl[2];
#pragma unroll
    for (int i = 0; i < 2; ++i) {
      const int ar = wr * 32 + i * 16 + (l & 15);
      ah[i] = *reinterpret_cast<const bf16x8*>(&As_h[ar * PIT + kk]);
      al[i] = *reinterpret_cast<const bf16x8*>(&As_l[ar * PIT + kk]);
      const int br = wc * 32 + i * 16 + (l & 15);
      bh[i] = *reinterpret_cast<const bf16x8*>(&Bs_h[br * PIT + kk]);
      bl[i] = *reinterpret_cast<const bf16x8*>(&Bs_l[br * PIT + kk]);
    }
#pragma unroll
    for (int i = 0; i < 2; ++i)
#pragma unroll
      for (int j = 0; j < 2; ++j) {
        acc[i][j] = __builtin_amdgcn_mfma_f32_16x16x32_bf16(ah[i], bh[j], acc[i][j], 0, 0, 0);
        acc[i][j] = __builtin_amdgcn_mfma_f32_16x16x32_bf16(ah[i], bl[j], acc[i][j], 0, 0, 0);
        acc[i][j] = __builtin_amdgcn_mfma_f32_16x16x32_bf16(al[i], bh[j], acc[i][j], 0, 0, 0);
      }
    __syncthreads();
  }

#pragma unroll
  for (int i = 0; i < 2; ++i)
#pragma unroll
    for (int j = 0; j < 2; ++j) {
      const int gn = n0 + wc * 32 + j * 16 + (l & 15);
      const float bv = bias[gn];
#pragma unroll
      for (int r = 0; r < 4; ++r) {
        const int gm = m0 + wr * 32 + i * 16 + (l >> 4) * 4 + r;
        OUT[(size_t)gm * 256 + gn] = acc[i][j][r] + bv + X[(size_t)gm * 256 + gn];
      }
    }
}

// Fused V + alpha + rescale, v2: Wv fragments prefetched to REGISTERS once per
// block (wave w owns 32 Wv-cols -> 32 bf16x8 = 128 VGPR), then grid-stride over
// row-tiles of 16 samples. 512 thr / 8 waves, grid 256, 2 tiles per block.
__global__ __launch_bounds__(512) void k_valpha(
    const float* __restrict__ X,
    const unsigned short* __restrict__ WvTh, const unsigned short* __restrict__ WvTl,
    float* __restrict__ F)
{
  __shared__ __align__(16) unsigned short Ash[32 * 256];
  __shared__ __align__(16) unsigned short Asl[32 * 256];
  __shared__ double part[2][16][8];
  __shared__ float als[16];
  const int t = threadIdx.x;          // 0..511
  const int l = t & 63, w = t >> 6;   // wave 0..7
  const int c = l & 15, g = l >> 4;
  const int nb = w * 32;              // this wave's Wv-col base

  // ---- prefetch B fragments (whole block covers all 256 Wv cols) ----
  bf16x8 bh[2][8], bl[2][8];
#pragma unroll
  for (int nf = 0; nf < 2; ++nf)
#pragma unroll
    for (int ks = 0; ks < 8; ++ks) {
      const int col = nb + nf * 16 + c;
      const int kof = ks * 32 + g * 8;
      bh[nf][ks] = *reinterpret_cast<const bf16x8*>(&WvTh[(size_t)col * 256 + kof]);
      bl[nf][ks] = *reinterpret_cast<const bf16x8*>(&WvTl[(size_t)col * 256 + kof]);
    }

  const int srow = t >> 4;            // 0..31 (staging row)
  const int q = t & 15;               // col-quad: cols [q*16, q*16+16)

  for (int tt = 0; tt < 2; ++tt) {
    const int r0 = (tt * 256 + blockIdx.x) * 16;

    // ---- stage A: rows 0..15 = x, 16..31 = f; keep f in regs ----
    float4 fv[4];
    {
      const float* src = (srow < 16) ? &X[(size_t)(r0 + srow) * 256]
                                     : &F[(size_t)(r0 + srow - 16) * 256];
#pragma unroll
      for (int i = 0; i < 4; ++i) {
        const float4 v = *reinterpret_cast<const float4*>(&src[q * 16 + i * 4]);
        fv[i] = v;
        const unsigned short h0 = f2bf(v.x), h1 = f2bf(v.y), h2 = f2bf(v.z), h3 = f2bf(v.w);
        uint2 hp, lp;
        hp.x = (unsigned)h0 | ((unsigned)h1 << 16);
        hp.y = (unsigned)h2 | ((unsigned)h3 << 16);
        lp.x = (unsigned)f2bf(v.x - bf2f(h0)) | ((unsigned)f2bf(v.y - bf2f(h1)) << 16);
        lp.y = (unsigned)f2bf(v.z - bf2f(h2)) | ((unsigned)f2bf(v.w - bf2f(h3)) << 16);
        const unsigned byte = (unsigned)(srow * 512 + q * 32 + i * 8) ^ ((srow & 7) << 4);
        *reinterpret_cast<uint2*>(((char*)Ash) + byte) = hp;
        *reinterpret_cast<uint2*>(((char*)Asl) + byte) = lp;
      }
    }
    __syncthreads();

    // ---- MFMA: Z = [x;f] @ Wv, square-accumulate in f64 ----
    double vs[2][4] = {};
#pragma unroll
    for (int nf = 0; nf < 2; ++nf) {
      f32x4 acc0 = {}, acc1 = {};
#pragma unroll
      for (int ks = 0; ks < 8; ++ks) {
        const int kof = ks * 32 + g * 8;
        const unsigned ab0 = (unsigned)(c * 512 + kof * 2) ^ ((c & 7) << 4);
        const unsigned ab1 = (unsigned)((c + 16) * 512 + kof * 2) ^ ((c & 7) << 4);
        const bf16x8 a0h = *reinterpret_cast<const bf16x8*>(((char*)Ash) + ab0);
        const bf16x8 a0l = *reinterpret_cast<const bf16x8*>(((char*)Asl) + ab0);
        const bf16x8 a1h = *reinterpret_cast<const bf16x8*>(((char*)Ash) + ab1);
        const bf16x8 a1l = *reinterpret_cast<const bf16x8*>(((char*)Asl) + ab1);
        acc0 = __builtin_amdgcn_mfma_f32_16x16x32_bf16(a0h, bh[nf][ks], acc0, 0, 0, 0);
        acc0 = __builtin_amdgcn_mfma_f32_16x16x32_bf16(a0h, bl[nf][ks], acc0, 0, 0, 0);
        acc0 = __builtin_amdgcn_mfma_f32_16x16x32_bf16(a0l, bh[nf][ks], acc0, 0, 0, 0);
        acc1 = __builtin_amdgcn_mfma_f32_16x16x32_bf16(a1h, bh[nf][ks], acc1, 0, 0, 0);
        acc1 = __builtin_amdgcn_mfma_f32_16x16x32_bf16(a1h, bl[nf][ks], acc1, 0, 0, 0);
        acc1 = __builtin_amdgcn_mfma_f32_16x16x32_bf16(a1l, bh[nf][ks], acc1, 0, 0, 0);
      }
#pragma unroll
      for (int r = 0; r < 4; ++r) {
        vs[0][r] += (double)acc0[r] * (double)acc0[r];
        vs[1][r] += (double)acc1[r] * (double)acc1[r];
      }
    }

    // reduce across the 16 C-cols (lanes sharing g)
#pragma unroll
    for (int s = 0; s < 2; ++s)
#pragma unroll
      for (int r = 0; r < 4; ++r) {
        double v = vs[s][r];
        v += __shfl_xor(v, 1);
        v += __shfl_xor(v, 2);
        v += __shfl_xor(v, 4);
        v += __shfl_xor(v, 8);
        vs[s][r] = v;
      }
    if (c == 0) {
#pragma unroll
      for (int r = 0; r < 4; ++r) {
        part[0][g * 4 + r][w] = vs[0][r];
        part[1][g * 4 + r][w] = vs[1][r];
      }
    }
    __syncthreads();

    if (t < 16) {
      double Vx = 0.0, Vf = 0.0;
#pragma unroll
      for (int i = 0; i < 8; ++i) { Vx += part[0][t][i]; Vf += part[1][t][i]; }
      const double tt2 = 0.99 * Vx;
      float a;
      if (Vf - tt2 > 0.0)        a = (float)sqrt(tt2 / Vf);  // Newton limit
      else if (tt2 - Vf > 1e-4)  a = 0.5f;                   // stuck-bisection case
      else                       a = 1.0f;                   // never masked
      als[t] = a;
    }
    __syncthreads();

    if (srow >= 16) {
      const int row = srow - 16;
      const float a = als[row];
      float* dst = &F[(size_t)(r0 + row) * 256];
#pragma unroll
      for (int i = 0; i < 4; ++i) {
        float4 v = fv[i];
        v.x *= a; v.y *= a; v.z *= a; v.w *= a;
        *reinterpret_cast<float4*>(&dst[q * 16 + i * 4]) = v;
      }
    }
    __syncthreads();  // LDS reuse across tiles
  }
}

extern "C" void kernel_launch(void* const* d_in, const int* in_sizes, int n_in,
                              void* d_out, int out_size, void* d_ws, size_t ws_size,
                              hipStream_t stream) {
  const float* x  = (const float*)d_in[0];
  const float* W1 = (const float*)d_in[1];
  const float* b1 = (const float*)d_in[2];
  const float* W2 = (const float*)d_in[3];
  const float* b2 = (const float*)d_in[4];
  const float* Wv = (const float*)d_in[5];
  float* out = (float*)d_out;

  char* ws = (char*)d_ws;
  unsigned short* Hh   = (unsigned short*)(ws);                          // 16.8 MB
  unsigned short* Hl   = (unsigned short*)(ws + 16777216);               // 16.8 MB
  unsigned short* W1Th = (unsigned short*)(ws + 33554432);
  unsigned short* W1Tl = (unsigned short*)(ws + 33554432 + 524288);
  unsigned short* W2Th = (unsigned short*)(ws + 33554432 + 2 * 524288);
  unsigned short* W2Tl = (unsigned short*)(ws + 33554432 + 3 * 524288);
  unsigned short* WvTh = (unsigned short*)(ws + 33554432 + 4 * 524288);
  unsigned short* WvTl = (unsigned short*)(ws + 33554432 + 4 * 524288 + 131072);

  k_split_all<<<dim3(2304), dim3(256), 0, stream>>>(W1, W2, Wv, W1Th, W1Tl, W2Th, W2Tl, WvTh, WvTl);

  k_gemm1 <<<dim3(1024 / 128, 8192 / 128), dim3(256), 0, stream>>>(x, W1Th, W1Tl, b1, Hh, Hl);
  k_gemm2 <<<dim3(256 / 64, 8192 / 64), dim3(256), 0, stream>>>(Hh, Hl, W2Th, W2Tl, b2, x, out);
  k_valpha<<<dim3(256), dim3(512), 0, stream>>>(x, WvTh, WvTl, out);
}